// Round 6
// baseline (587.677 us; speedup 1.0000x reference)
//
#include <hip/hip_runtime.h>

#define NN 100000
#define EE 1600000
#define ELLW 64   // max in-degree; Poisson(16) over 100K nodes -> max ~40, 64 safe
#define NXCD 8
#define RNG ((NN + NXCD - 1) / NXCD)   // 12500 nodes per XCD partition

// bf16 round-to-nearest-even pack of two floats -> (lo=a, hi=b)
__device__ __forceinline__ unsigned int pack_bf2(float a, float b) {
    unsigned int ua = __float_as_uint(a);
    ua += 0x7FFFu + ((ua >> 16) & 1u);
    unsigned int ub = __float_as_uint(b);
    ub += 0x7FFFu + ((ub >> 16) & 1u);
    return (ua >> 16) | (ub & 0xFFFF0000u);
}

// ---------------- XCD-partitioned single-pass ELL build ----------------
// blockIdx&7 ~ XCD id (round-robin dispatch heuristic; correctness never
// depends on it). Residue-r blocks own dst/src range r: ELL write set per
// XCD = 3.2 MB -> L2-resident. Edge-list reads use NONTEMPORAL loads so the
// 12.8 MB/XCD stream does not evict the partially-filled dirty ELL lines
// (that eviction was the 129 MB write amplification in r5).
__global__ __launch_bounds__(256) void k_build(const int* __restrict__ src, const int* __restrict__ dst,
                                               int* __restrict__ din, int* __restrict__ dout,
                                               int* __restrict__ ell, int e) {
    int r = blockIdx.x & (NXCD - 1);
    int slice = blockIdx.x >> 3;
    int i = slice * 256 + threadIdx.x;
    if (i >= e) return;
    int s = __builtin_nontemporal_load(&src[i]);
    int d = __builtin_nontemporal_load(&dst[i]);
    int lo = r * RNG, hi = lo + RNG;
    if (d >= lo && d < hi) {
        int p = atomicAdd(&din[d], 1);
        if (p < ELLW) ell[(size_t)d * ELLW + p] = s;
    }
    if (s >= lo && s < hi) {
        atomicAdd(&dout[s], 1);
    }
}

// ---------------- normalization scales ----------------
__global__ __launch_bounds__(256) void k_rsqrt(const int* __restrict__ dout, const int* __restrict__ din,
                                               float* __restrict__ so, float* __restrict__ si, int n) {
    int i = blockIdx.x * 256 + threadIdx.x;
    if (i < n) {
        so[i] = rsqrtf((float)max(1, dout[i]));
        si[i] = rsqrtf((float)max(1, din[i]));
    }
}

// ---------------- GEMM: Ybf16[n x 128] = (X[n x 128] * scale[row]) @ W[128 x 128] ----------------
__global__ __launch_bounds__(512) void k_gemm128(const float* __restrict__ X, const float* __restrict__ scale,
                                                 const float* __restrict__ W, unsigned int* __restrict__ Y, int n) {
    __shared__ float Xs[128 * 64];
    int tid = threadIdx.x;
    int row0 = blockIdx.x * 64;
    const float4* X4 = (const float4*)X;
    for (int idx = tid; idx < 2048; idx += 512) {
        int r = idx & 63, c4 = idx >> 6;
        int row = row0 + r;
        float4 v = make_float4(0.f, 0.f, 0.f, 0.f);
        float s = 0.f;
        if (row < n) { v = X4[(size_t)row * 32 + c4]; s = scale[row]; }
        Xs[(c4 * 4 + 0) * 64 + r] = v.x * s;
        Xs[(c4 * 4 + 1) * 64 + r] = v.y * s;
        Xs[(c4 * 4 + 2) * 64 + r] = v.z * s;
        Xs[(c4 * 4 + 3) * 64 + r] = v.w * s;
    }
    __syncthreads();
    int cg = tid & 31;
    int rg = tid >> 5;
    float a00=0,a01=0,a02=0,a03=0, a10=0,a11=0,a12=0,a13=0;
    float a20=0,a21=0,a22=0,a23=0, a30=0,a31=0,a32=0,a33=0;
    const float4* W4 = (const float4*)W;
#pragma unroll 4
    for (int k = 0; k < 128; ++k) {
        float4 xv = *(const float4*)&Xs[k * 64 + rg * 4];
        float4 wv = W4[k * 32 + cg];
        a00 += xv.x * wv.x; a01 += xv.x * wv.y; a02 += xv.x * wv.z; a03 += xv.x * wv.w;
        a10 += xv.y * wv.x; a11 += xv.y * wv.y; a12 += xv.y * wv.z; a13 += xv.y * wv.w;
        a20 += xv.z * wv.x; a21 += xv.z * wv.y; a22 += xv.z * wv.z; a23 += xv.z * wv.w;
        a30 += xv.w * wv.x; a31 += xv.w * wv.y; a32 += xv.w * wv.z; a33 += xv.w * wv.w;
    }
    int rbase = row0 + rg * 4;
    uint2* Y2 = (uint2*)Y;
    if (rbase + 0 < n) Y2[(size_t)(rbase + 0) * 32 + cg] = make_uint2(pack_bf2(a00, a01), pack_bf2(a02, a03));
    if (rbase + 1 < n) Y2[(size_t)(rbase + 1) * 32 + cg] = make_uint2(pack_bf2(a10, a11), pack_bf2(a12, a13));
    if (rbase + 2 < n) Y2[(size_t)(rbase + 2) * 32 + cg] = make_uint2(pack_bf2(a20, a21), pack_bf2(a22, a23));
    if (rbase + 3 < n) Y2[(size_t)(rbase + 3) * 32 + cg] = make_uint2(pack_bf2(a30, a31), pack_bf2(a32, a33));
}

// ---------------- GEMM: Y[n x 40] f32 = (X[n x 128] * scale[row]) @ W[128 x 40] ----------------
__global__ __launch_bounds__(320) void k_gemm40(const float* __restrict__ X, const float* __restrict__ scale,
                                                const float* __restrict__ W, float* __restrict__ Y, int n) {
    __shared__ float Xs[128 * 64];
    int tid = threadIdx.x;
    int row0 = blockIdx.x * 64;
    const float4* X4 = (const float4*)X;
    for (int idx = tid; idx < 2048; idx += 320) {
        int r = idx & 63, c4 = idx >> 6;
        int row = row0 + r;
        float4 v = make_float4(0.f, 0.f, 0.f, 0.f);
        float s = 0.f;
        if (row < n) { v = X4[(size_t)row * 32 + c4]; s = scale[row]; }
        Xs[(c4 * 4 + 0) * 64 + r] = v.x * s;
        Xs[(c4 * 4 + 1) * 64 + r] = v.y * s;
        Xs[(c4 * 4 + 2) * 64 + r] = v.z * s;
        Xs[(c4 * 4 + 3) * 64 + r] = v.w * s;
    }
    __syncthreads();
    int cg = tid % 20;
    int rg = tid / 20;
    float a0x=0,a0y=0, a1x=0,a1y=0, a2x=0,a2y=0, a3x=0,a3y=0;
    const float2* W2 = (const float2*)W;
#pragma unroll 4
    for (int k = 0; k < 128; ++k) {
        float4 xv = *(const float4*)&Xs[k * 64 + rg * 4];
        float2 wv = W2[k * 20 + cg];
        a0x += xv.x * wv.x; a0y += xv.x * wv.y;
        a1x += xv.y * wv.x; a1y += xv.y * wv.y;
        a2x += xv.z * wv.x; a2y += xv.z * wv.y;
        a3x += xv.w * wv.x; a3y += xv.w * wv.y;
    }
    int rbase = row0 + rg * 4;
    float2* Y2 = (float2*)Y;
    if (rbase + 0 < n) Y2[(size_t)(rbase + 0) * 20 + cg] = make_float2(a0x, a0y);
    if (rbase + 1 < n) Y2[(size_t)(rbase + 1) * 20 + cg] = make_float2(a1x, a1y);
    if (rbase + 2 < n) Y2[(size_t)(rbase + 2) * 20 + cg] = make_float2(a2x, a2y);
    if (rbase + 3 < n) Y2[(size_t)(rbase + 3) * 20 + cg] = make_float2(a3x, a3y);
}

// ---------------- gather-aggregate (ELL), 128 cols bf16 payload, f32 accumulate ----------------
__global__ __launch_bounds__(256) void k_gather128(const unsigned int* __restrict__ h, const int* __restrict__ din,
                                                   const int* __restrict__ ell, const float* __restrict__ si,
                                                   const float* __restrict__ b, float* __restrict__ out,
                                                   int n, int do_relu) {
    int wv = threadIdx.x >> 6, lane = threadIdx.x & 63;
    int v = blockIdx.x * 4 + wv;
    if (v >= n) return;
    int cnt = min(din[v], ELLW);
    int cl = ell[(size_t)v * ELLW + lane];   // full neighbor list in one wave load
    float sx = 0.f, sy = 0.f;
    for (int j = 0; j < cnt; j += 8) {
        int cc[8]; float mk[8]; unsigned int t[8];
#pragma unroll
        for (int k = 0; k < 8; ++k) {
            int jj = j + k;
            cc[k] = __shfl(cl, jj < cnt ? jj : cnt - 1);
            mk[k] = (jj < cnt) ? 1.f : 0.f;
        }
#pragma unroll
        for (int k = 0; k < 8; ++k)
            t[k] = h[(size_t)cc[k] * 64 + lane];
#pragma unroll
        for (int k = 0; k < 8; ++k) {
            float x = __uint_as_float(t[k] << 16);
            float y = __uint_as_float(t[k] & 0xFFFF0000u);
            sx = fmaf(mk[k], x, sx);
            sy = fmaf(mk[k], y, sy);
        }
    }
    float sc = si[v];
    float2 bb = ((const float2*)b)[lane];
    float ox = sx * sc + bb.x;
    float oy = sy * sc + bb.y;
    if (do_relu) { ox = fmaxf(ox, 0.f); oy = fmaxf(oy, 0.f); }
    ((float2*)out)[(size_t)v * 64 + lane] = make_float2(ox, oy);
}

// ---------------- gather-aggregate (ELL), 40 cols f32 (final layer) ----------------
__global__ __launch_bounds__(256) void k_gather40(const float* __restrict__ h, const int* __restrict__ din,
                                                  const int* __restrict__ ell, const float* __restrict__ si,
                                                  const float* __restrict__ b, float* __restrict__ out, int n) {
    int wv = threadIdx.x >> 6, lane = threadIdx.x & 63;
    int v = blockIdx.x * 4 + wv;
    if (v >= n) return;
    int cnt = min(din[v], ELLW);
    int cl = ell[(size_t)v * ELLW + lane];
    float s = 0.f;
    for (int j = 0; j < cnt; j += 8) {
        int cc[8]; float mk[8]; float t[8];
#pragma unroll
        for (int k = 0; k < 8; ++k) {
            int jj = j + k;
            cc[k] = __shfl(cl, jj < cnt ? jj : cnt - 1);
            mk[k] = (jj < cnt) ? 1.f : 0.f;
        }
        if (lane < 40) {
#pragma unroll
            for (int k = 0; k < 8; ++k) t[k] = h[(size_t)cc[k] * 40 + lane];
#pragma unroll
            for (int k = 0; k < 8; ++k) s = fmaf(mk[k], t[k], s);
        }
    }
    if (lane < 40) {
        out[(size_t)v * 40 + lane] = s * si[v] + b[lane];
    }
}

extern "C" void kernel_launch(void* const* d_in, const int* in_sizes, int n_in,
                              void* d_out, int out_size, void* d_ws, size_t ws_size,
                              hipStream_t stream) {
    const float* feat = (const float*)d_in[0];
    const int*   src  = (const int*)d_in[1];
    const int*   dst  = (const int*)d_in[2];
    const float* W0   = (const float*)d_in[3];
    const float* b0   = (const float*)d_in[4];
    const float* W1   = (const float*)d_in[5];
    const float* b1   = (const float*)d_in[6];
    const float* W2   = (const float*)d_in[7];
    const float* b2   = (const float*)d_in[8];
    float* out = (float*)d_out;

    char* w = (char*)d_ws;
    int*   din       = (int*)w;    w += (size_t)NN * 4;
    int*   dout      = (int*)w;    w += (size_t)NN * 4;
    float* scale_out = (float*)w;  w += (size_t)NN * 4;
    float* scale_in  = (float*)w;  w += (size_t)NN * 4;
    int*   ell       = (int*)w;    w += (size_t)NN * ELLW * 4;       // 25.6 MB
    unsigned int* h2 = (unsigned int*)w; w += (size_t)NN * 128 * 2;  // bf16 rows, 25.6 MB
    float* h40       = (float*)w;  w += (size_t)NN * 40 * 4;         // 16 MB
    float* agg       = (float*)w;  w += (size_t)NN * 128 * 4;        // 51.2 MB

    // zero the two degree counters (contiguous at base)
    hipMemsetAsync(d_ws, 0, (size_t)NN * 8, stream);

    int slices = (EE + 255) / 256;
    k_build<<<slices * NXCD, 256, 0, stream>>>(src, dst, din, dout, ell, EE);
    k_rsqrt<<<(NN + 255) / 256, 256, 0, stream>>>(dout, din, scale_out, scale_in, NN);

    int gemm_grid = (NN + 63) / 64;
    int gath_grid = (NN + 3) / 4;

    // layer 0
    k_gemm128<<<gemm_grid, 512, 0, stream>>>(feat, scale_out, W0, h2, NN);
    k_gather128<<<gath_grid, 256, 0, stream>>>(h2, din, ell, scale_in, b0, agg, NN, 1);
    // layer 1
    k_gemm128<<<gemm_grid, 512, 0, stream>>>(agg, scale_out, W1, h2, NN);
    k_gather128<<<gath_grid, 256, 0, stream>>>(h2, din, ell, scale_in, b1, agg, NN, 1);
    // layer 2 (40 cols f32, no relu), writes d_out directly
    k_gemm40<<<gemm_grid, 320, 0, stream>>>(agg, scale_out, W2, h40, NN);
    k_gather40<<<gath_grid, 256, 0, stream>>>(h40, din, ell, scale_in, b2, out, NN);
}

// Round 8
// 579.925 us; speedup vs baseline: 1.0134x; 1.0134x over previous
//
#include <hip/hip_runtime.h>

#define NN 100000
#define EE 1600000
#define ELLW 64   // max in-degree; Poisson(16) over 100K nodes -> max ~40, 64 safe
#define NXCD 8
#define RNG ((NN + NXCD - 1) / NXCD)   // 12500 nodes per XCD partition
#define GEMMN ((NN + 63) / 64)         // 1563 gemm blocks
#define BUILDN ((EE / 256) * NXCD)     // 50000 build blocks

// bf16 round-to-nearest-even pack of two floats -> (lo=a, hi=b)
__device__ __forceinline__ unsigned int pack_bf2(float a, float b) {
    unsigned int ua = __float_as_uint(a);
    ua += 0x7FFFu + ((ua >> 16) & 1u);
    unsigned int ub = __float_as_uint(b);
    ub += 0x7FFFu + ((ub >> 16) & 1u);
    return (ua >> 16) | (ub & 0xFFFF0000u);
}

// ---------------- GEMM body: Ybf16[64 rows x 128] = (X*scale?) @ W, 256 threads ----------------
__device__ __forceinline__ void gemm128_body(const float* __restrict__ X, const int* __restrict__ dout,
                                             const float* __restrict__ W, unsigned int* __restrict__ Y,
                                             int n, int row0, int tid, float* Xs, int scaled) {
    const float4* X4 = (const float4*)X;
#pragma unroll
    for (int idx = tid; idx < 2048; idx += 256) {
        int r = idx & 63, c4 = idx >> 6;
        int row = row0 + r;
        float4 v = make_float4(0.f, 0.f, 0.f, 0.f);
        float s = 0.f;
        if (row < n) {
            v = X4[(size_t)row * 32 + c4];
            s = scaled ? rsqrtf((float)max(1, dout[row])) : 1.f;
        }
        Xs[(c4 * 4 + 0) * 64 + r] = v.x * s;
        Xs[(c4 * 4 + 1) * 64 + r] = v.y * s;
        Xs[(c4 * 4 + 2) * 64 + r] = v.z * s;
        Xs[(c4 * 4 + 3) * 64 + r] = v.w * s;
    }
    __syncthreads();
    int cg = tid & 15;   // 16 col groups x 8 cols
    int rg = tid >> 4;   // 16 row groups x 4 rows
    float a[4][8];
#pragma unroll
    for (int r = 0; r < 4; ++r)
#pragma unroll
        for (int c = 0; c < 8; ++c) a[r][c] = 0.f;
    const float4* W4 = (const float4*)W;
#pragma unroll 2
    for (int k = 0; k < 128; ++k) {
        float4 xv = *(const float4*)&Xs[k * 64 + rg * 4];
        float4 w0 = W4[k * 32 + cg * 2];
        float4 w1 = W4[k * 32 + cg * 2 + 1];
        float xr[4] = {xv.x, xv.y, xv.z, xv.w};
        float wc[8] = {w0.x, w0.y, w0.z, w0.w, w1.x, w1.y, w1.z, w1.w};
#pragma unroll
        for (int r = 0; r < 4; ++r)
#pragma unroll
            for (int c = 0; c < 8; ++c) a[r][c] = fmaf(xr[r], wc[c], a[r][c]);
    }
    int rbase = row0 + rg * 4;
    uint4* Y4 = (uint4*)Y;   // 16 uint4 per 128-col bf16 row
#pragma unroll
    for (int r = 0; r < 4; ++r) {
        if (rbase + r < n) {
            Y4[(size_t)(rbase + r) * 16 + cg] =
                make_uint4(pack_bf2(a[r][0], a[r][1]), pack_bf2(a[r][2], a[r][3]),
                           pack_bf2(a[r][4], a[r][5]), pack_bf2(a[r][6], a[r][7]));
        }
    }
}

// ---------------- fused: GEMM0 (unscaled feat@W0, independent) + XCD-partitioned ELL build ----------------
__global__ __launch_bounds__(256) void k_build_gemm0(const int* __restrict__ src, const int* __restrict__ dst,
                                                     int* __restrict__ din, int* __restrict__ dout,
                                                     int* __restrict__ ell,
                                                     const float* __restrict__ X, const float* __restrict__ W,
                                                     unsigned int* __restrict__ Y) {
    __shared__ float Xs[128 * 64];
    int tid = threadIdx.x;
    if (blockIdx.x < GEMMN) {
        gemm128_body(X, nullptr, W, Y, NN, blockIdx.x * 64, tid, Xs, 0);
        return;
    }
    int idx = blockIdx.x - GEMMN;
    int r = idx & (NXCD - 1);
    int slice = idx >> 3;
    int i = slice * 256 + tid;
    if (i >= EE) return;
    int s = __builtin_nontemporal_load(&src[i]);
    int d = __builtin_nontemporal_load(&dst[i]);
    int lo = r * RNG, hi = lo + RNG;
    if (d >= lo && d < hi) {
        int p = atomicAdd(&din[d], 1);
        if (p < ELLW) ell[(size_t)d * ELLW + p] = s;
    }
    if (s >= lo && s < hi) {
        atomicAdd(&dout[s], 1);
    }
}

// ---------------- standalone GEMM (layer 1): scaled by rsqrt(dout) inline ----------------
__global__ __launch_bounds__(256) void k_gemm128(const float* __restrict__ X, const int* __restrict__ dout,
                                                 const float* __restrict__ W, unsigned int* __restrict__ Y, int n) {
    __shared__ float Xs[128 * 64];
    gemm128_body(X, dout, W, Y, n, blockIdx.x * 64, threadIdx.x, Xs, 1);
}

// ---------------- GEMM: Y[n x 40] f32 = (X * rsqrt(dout)) @ W[128 x 40], 320 threads ----------------
__global__ __launch_bounds__(320) void k_gemm40(const float* __restrict__ X, const int* __restrict__ dout,
                                                const float* __restrict__ W, float* __restrict__ Y, int n) {
    __shared__ float Xs[128 * 64];
    int tid = threadIdx.x;
    int row0 = blockIdx.x * 64;
    const float4* X4 = (const float4*)X;
    for (int idx = tid; idx < 2048; idx += 320) {
        int r = idx & 63, c4 = idx >> 6;
        int row = row0 + r;
        float4 v = make_float4(0.f, 0.f, 0.f, 0.f);
        float s = 0.f;
        if (row < n) { v = X4[(size_t)row * 32 + c4]; s = rsqrtf((float)max(1, dout[row])); }
        Xs[(c4 * 4 + 0) * 64 + r] = v.x * s;
        Xs[(c4 * 4 + 1) * 64 + r] = v.y * s;
        Xs[(c4 * 4 + 2) * 64 + r] = v.z * s;
        Xs[(c4 * 4 + 3) * 64 + r] = v.w * s;
    }
    __syncthreads();
    int cg = tid % 20;
    int rg = tid / 20;
    float a0x=0,a0y=0, a1x=0,a1y=0, a2x=0,a2y=0, a3x=0,a3y=0;
    const float2* W2 = (const float2*)W;
#pragma unroll 4
    for (int k = 0; k < 128; ++k) {
        float4 xv = *(const float4*)&Xs[k * 64 + rg * 4];
        float2 wv = W2[k * 20 + cg];
        a0x += xv.x * wv.x; a0y += xv.x * wv.y;
        a1x += xv.y * wv.x; a1y += xv.y * wv.y;
        a2x += xv.z * wv.x; a2y += xv.z * wv.y;
        a3x += xv.w * wv.x; a3y += xv.w * wv.y;
    }
    int rbase = row0 + rg * 4;
    float2* Y2 = (float2*)Y;
    if (rbase + 0 < n) Y2[(size_t)(rbase + 0) * 20 + cg] = make_float2(a0x, a0y);
    if (rbase + 1 < n) Y2[(size_t)(rbase + 1) * 20 + cg] = make_float2(a1x, a1y);
    if (rbase + 2 < n) Y2[(size_t)(rbase + 2) * 20 + cg] = make_float2(a2x, a2y);
    if (rbase + 3 < n) Y2[(size_t)(rbase + 3) * 20 + cg] = make_float2(a3x, a3y);
}

// ---------------- gather-aggregate (ELL), 128 cols bf16, si inline; optional per-neighbor so ----------------
__global__ __launch_bounds__(256) void k_gather128(const unsigned int* __restrict__ h, const int* __restrict__ din,
                                                   const int* __restrict__ dout, const int* __restrict__ ell,
                                                   const float* __restrict__ b, float* __restrict__ out,
                                                   int n, int do_relu, int so_mode) {
    int wv = threadIdx.x >> 6, lane = threadIdx.x & 63;
    int v = blockIdx.x * 4 + wv;
    if (v >= n) return;
    int dv = din[v];
    int cnt = min(dv, ELLW);
    int cl = ell[(size_t)v * ELLW + lane];   // full neighbor list, one wave load
    // ELL slots >= cnt are UNINITIALIZED (0xAA poison) -> clamp before any
    // dereference; shuffles only ever select lanes < cnt so value is unused.
    int cls = (lane < cnt) ? cl : 0;
    float scl = 1.f;
    if (so_mode) scl = rsqrtf((float)max(1, dout[cls]));   // per-neighbor out-scale
    float sx = 0.f, sy = 0.f;
    for (int j = 0; j < cnt; j += 8) {
        int cc[8]; float mk[8]; unsigned int t[8];
#pragma unroll
        for (int k = 0; k < 8; ++k) {
            int jj = j + k;
            int jc = jj < cnt ? jj : cnt - 1;
            cc[k] = __shfl(cls, jc);
            float sw = __shfl(scl, jc);
            mk[k] = (jj < cnt) ? sw : 0.f;
        }
#pragma unroll
        for (int k = 0; k < 8; ++k)
            t[k] = h[(size_t)cc[k] * 64 + lane];
#pragma unroll
        for (int k = 0; k < 8; ++k) {
            float x = __uint_as_float(t[k] << 16);
            float y = __uint_as_float(t[k] & 0xFFFF0000u);
            sx = fmaf(mk[k], x, sx);
            sy = fmaf(mk[k], y, sy);
        }
    }
    float sc = rsqrtf((float)max(1, dv));
    float2 bb = ((const float2*)b)[lane];
    float ox = sx * sc + bb.x;
    float oy = sy * sc + bb.y;
    if (do_relu) { ox = fmaxf(ox, 0.f); oy = fmaxf(oy, 0.f); }
    ((float2*)out)[(size_t)v * 64 + lane] = make_float2(ox, oy);
}

// ---------------- gather-aggregate (ELL), 40 cols f32, si inline (final layer) ----------------
__global__ __launch_bounds__(256) void k_gather40(const float* __restrict__ h, const int* __restrict__ din,
                                                  const int* __restrict__ ell,
                                                  const float* __restrict__ b, float* __restrict__ out, int n) {
    int wv = threadIdx.x >> 6, lane = threadIdx.x & 63;
    int v = blockIdx.x * 4 + wv;
    if (v >= n) return;
    int dv = din[v];
    int cnt = min(dv, ELLW);
    int cl = ell[(size_t)v * ELLW + lane];
    int cls = (lane < cnt) ? cl : 0;
    float s = 0.f;
    for (int j = 0; j < cnt; j += 8) {
        int cc[8]; float mk[8]; float t[8];
#pragma unroll
        for (int k = 0; k < 8; ++k) {
            int jj = j + k;
            cc[k] = __shfl(cls, jj < cnt ? jj : cnt - 1);
            mk[k] = (jj < cnt) ? 1.f : 0.f;
        }
        if (lane < 40) {
#pragma unroll
            for (int k = 0; k < 8; ++k) t[k] = h[(size_t)cc[k] * 40 + lane];
#pragma unroll
            for (int k = 0; k < 8; ++k) s = fmaf(mk[k], t[k], s);
        }
    }
    if (lane < 40) {
        out[(size_t)v * 40 + lane] = s * rsqrtf((float)max(1, dv)) + b[lane];
    }
}

extern "C" void kernel_launch(void* const* d_in, const int* in_sizes, int n_in,
                              void* d_out, int out_size, void* d_ws, size_t ws_size,
                              hipStream_t stream) {
    const float* feat = (const float*)d_in[0];
    const int*   src  = (const int*)d_in[1];
    const int*   dst  = (const int*)d_in[2];
    const float* W0   = (const float*)d_in[3];
    const float* b0   = (const float*)d_in[4];
    const float* W1   = (const float*)d_in[5];
    const float* b1   = (const float*)d_in[6];
    const float* W2   = (const float*)d_in[7];
    const float* b2   = (const float*)d_in[8];
    float* out = (float*)d_out;

    char* w = (char*)d_ws;
    int*   din       = (int*)w;    w += (size_t)NN * 4;
    int*   dout      = (int*)w;    w += (size_t)NN * 4;
    int*   ell       = (int*)w;    w += (size_t)NN * ELLW * 4;       // 25.6 MB
    unsigned int* h2 = (unsigned int*)w; w += (size_t)NN * 128 * 2;  // bf16 rows, 25.6 MB
    float* h40       = (float*)w;  w += (size_t)NN * 40 * 4;         // 16 MB
    float* agg       = (float*)w;  w += (size_t)NN * 128 * 4;        // 51.2 MB

    // zero the two degree counters (contiguous at base)
    hipMemsetAsync(d_ws, 0, (size_t)NN * 8, stream);

    int gath_grid = (NN + 3) / 4;

    // fused: GEMM0 (unscaled feat@W0 -> h2) + ELL/degree build (independent halves)
    k_build_gemm0<<<GEMMN + BUILDN, 256, 0, stream>>>(src, dst, din, dout, ell, feat, W0, h2);
    // layer 0 gather: applies per-neighbor so = rsqrt(dout[u]) and si inline
    k_gather128<<<gath_grid, 256, 0, stream>>>(h2, din, dout, ell, b0, agg, NN, 1, 1);
    // layer 1: gemm scales rows by rsqrt(dout) inline
    k_gemm128<<<GEMMN, 256, 0, stream>>>(agg, dout, W1, h2, NN);
    k_gather128<<<gath_grid, 256, 0, stream>>>(h2, din, dout, ell, b1, agg, NN, 1, 0);
    // layer 2 (40 cols f32, no relu), writes d_out directly
    k_gemm40<<<GEMMN, 320, 0, stream>>>(agg, dout, W2, h40, NN);
    k_gather40<<<gath_grid, 256, 0, stream>>>(h40, din, ell, b2, out, NN);
}

// Round 9
// 569.017 us; speedup vs baseline: 1.0328x; 1.0192x over previous
//
#include <hip/hip_runtime.h>

#define NN 100000
#define EE 1600000
#define ELLW 64   // max in-degree; Poisson(16) over 100K nodes -> max ~40, 64 safe
#define NXCD 8
#define RNG ((NN + NXCD - 1) / NXCD)   // 12500 nodes per XCD partition
#define GEMMN ((NN + 31) / 32)         // 3125 gemm blocks (32-row tiles, 16 KB LDS)
#define BUILDN ((EE / 256) * NXCD)     // 50000 build blocks
#define H40P 48                        // h40 row padded to 48 floats = 192 B = 3 aligned lines

// bf16 round-to-nearest-even pack of two floats -> (lo=a, hi=b)
__device__ __forceinline__ unsigned int pack_bf2(float a, float b) {
    unsigned int ua = __float_as_uint(a);
    ua += 0x7FFFu + ((ua >> 16) & 1u);
    unsigned int ub = __float_as_uint(b);
    ub += 0x7FFFu + ((ub >> 16) & 1u);
    return (ua >> 16) | (ub & 0xFFFF0000u);
}

__device__ __forceinline__ void nt_store_f2(float* p, float x, float y) {
    unsigned long long v = (unsigned long long)__float_as_uint(x) |
                           ((unsigned long long)__float_as_uint(y) << 32);
    __builtin_nontemporal_store(v, (unsigned long long*)p);
}

// ---------------- GEMM body: Ybf16[32 rows x 128] = (X*scale?) @ W, 256 threads, 16 KB LDS ----
__device__ __forceinline__ void gemm128_body(const float* __restrict__ X, const int* __restrict__ dout,
                                             const float* __restrict__ W, unsigned int* __restrict__ Y,
                                             int n, int row0, int tid, float* Xs, int scaled) {
    const float4* X4 = (const float4*)X;
#pragma unroll
    for (int idx = tid; idx < 1024; idx += 256) {
        int r = idx & 31, c4 = idx >> 5;
        int row = row0 + r;
        float4 v = make_float4(0.f, 0.f, 0.f, 0.f);
        float s = 0.f;
        if (row < n) {
            v = X4[(size_t)row * 32 + c4];
            s = scaled ? rsqrtf((float)max(1, dout[row])) : 1.f;
        }
        Xs[(c4 * 4 + 0) * 32 + r] = v.x * s;
        Xs[(c4 * 4 + 1) * 32 + r] = v.y * s;
        Xs[(c4 * 4 + 2) * 32 + r] = v.z * s;
        Xs[(c4 * 4 + 3) * 32 + r] = v.w * s;
    }
    __syncthreads();
    int cg = tid & 31;   // cols 4cg..4cg+3
    int rg = tid >> 5;   // rows 4rg..4rg+3
    float a[4][4];
#pragma unroll
    for (int r = 0; r < 4; ++r)
#pragma unroll
        for (int c = 0; c < 4; ++c) a[r][c] = 0.f;
    const float4* W4 = (const float4*)W;
#pragma unroll 4
    for (int k = 0; k < 128; ++k) {
        float4 xv = *(const float4*)&Xs[k * 32 + rg * 4];
        float4 wv = W4[k * 32 + cg];
        float xr[4] = {xv.x, xv.y, xv.z, xv.w};
        float wc[4] = {wv.x, wv.y, wv.z, wv.w};
#pragma unroll
        for (int r = 0; r < 4; ++r)
#pragma unroll
            for (int c = 0; c < 4; ++c) a[r][c] = fmaf(xr[r], wc[c], a[r][c]);
    }
    int rbase = row0 + rg * 4;
    uint2* Y2 = (uint2*)Y;   // 32 uint2 per 128-col bf16 row
#pragma unroll
    for (int r = 0; r < 4; ++r) {
        if (rbase + r < n) {
            Y2[(size_t)(rbase + r) * 32 + cg] =
                make_uint2(pack_bf2(a[r][0], a[r][1]), pack_bf2(a[r][2], a[r][3]));
        }
    }
}

// ---------------- fused: GEMM0 (unscaled feat@W0) + XCD-partitioned ELL build ----------------
// 16 KB LDS -> 8 blocks/CU (wave cap), build blocks keep full occupancy.
__global__ __launch_bounds__(256) void k_build_gemm0(const int* __restrict__ src, const int* __restrict__ dst,
                                                     int* __restrict__ din, int* __restrict__ dout,
                                                     int* __restrict__ ell,
                                                     const float* __restrict__ X, const float* __restrict__ W,
                                                     unsigned int* __restrict__ Y) {
    __shared__ float Xs[128 * 32];
    int tid = threadIdx.x;
    if (blockIdx.x < GEMMN) {
        gemm128_body(X, nullptr, W, Y, NN, blockIdx.x * 32, tid, Xs, 0);
        return;
    }
    int idx = blockIdx.x - GEMMN;
    int r = idx & (NXCD - 1);
    int slice = idx >> 3;
    int i = slice * 256 + tid;
    if (i >= EE) return;
    int s = __builtin_nontemporal_load(&src[i]);
    int d = __builtin_nontemporal_load(&dst[i]);
    int lo = r * RNG, hi = lo + RNG;
    if (d >= lo && d < hi) {
        int p = atomicAdd(&din[d], 1);
        if (p < ELLW) ell[(size_t)d * ELLW + p] = s;
    }
    if (s >= lo && s < hi) {
        atomicAdd(&dout[s], 1);
    }
}

// ---------------- standalone GEMM (layer 1): scaled by rsqrt(dout) inline ----------------
__global__ __launch_bounds__(256) void k_gemm128(const float* __restrict__ X, const int* __restrict__ dout,
                                                 const float* __restrict__ W, unsigned int* __restrict__ Y, int n) {
    __shared__ float Xs[128 * 32];
    gemm128_body(X, dout, W, Y, n, blockIdx.x * 32, threadIdx.x, Xs, 1);
}

// ---------------- GEMM: Y[n x 48pad] f32 = (X * rsqrt(dout)) @ W[128 x 40], 320 threads ------
__global__ __launch_bounds__(320) void k_gemm40(const float* __restrict__ X, const int* __restrict__ dout,
                                                const float* __restrict__ W, float* __restrict__ Y, int n) {
    __shared__ float Xs[128 * 64];
    int tid = threadIdx.x;
    int row0 = blockIdx.x * 64;
    const float4* X4 = (const float4*)X;
    for (int idx = tid; idx < 2048; idx += 320) {
        int r = idx & 63, c4 = idx >> 6;
        int row = row0 + r;
        float4 v = make_float4(0.f, 0.f, 0.f, 0.f);
        float s = 0.f;
        if (row < n) { v = X4[(size_t)row * 32 + c4]; s = rsqrtf((float)max(1, dout[row])); }
        Xs[(c4 * 4 + 0) * 64 + r] = v.x * s;
        Xs[(c4 * 4 + 1) * 64 + r] = v.y * s;
        Xs[(c4 * 4 + 2) * 64 + r] = v.z * s;
        Xs[(c4 * 4 + 3) * 64 + r] = v.w * s;
    }
    __syncthreads();
    int cg = tid % 20;
    int rg = tid / 20;
    float a0x=0,a0y=0, a1x=0,a1y=0, a2x=0,a2y=0, a3x=0,a3y=0;
    const float2* W2 = (const float2*)W;
#pragma unroll 4
    for (int k = 0; k < 128; ++k) {
        float4 xv = *(const float4*)&Xs[k * 64 + rg * 4];
        float2 wv = W2[k * 20 + cg];
        a0x += xv.x * wv.x; a0y += xv.x * wv.y;
        a1x += xv.y * wv.x; a1y += xv.y * wv.y;
        a2x += xv.z * wv.x; a2y += xv.z * wv.y;
        a3x += xv.w * wv.x; a3y += xv.w * wv.y;
    }
    int rbase = row0 + rg * 4;
    float2* Y2 = (float2*)Y;   // row stride H40P/2 = 24 float2
    if (rbase + 0 < n) Y2[(size_t)(rbase + 0) * 24 + cg] = make_float2(a0x, a0y);
    if (rbase + 1 < n) Y2[(size_t)(rbase + 1) * 24 + cg] = make_float2(a1x, a1y);
    if (rbase + 2 < n) Y2[(size_t)(rbase + 2) * 24 + cg] = make_float2(a2x, a2y);
    if (rbase + 3 < n) Y2[(size_t)(rbase + 3) * 24 + cg] = make_float2(a3x, a3y);
}

// ---------------- gather-aggregate (ELL), 128 cols bf16, si inline; optional per-neighbor so ----
__global__ __launch_bounds__(256) void k_gather128(const unsigned int* __restrict__ h, const int* __restrict__ din,
                                                   const int* __restrict__ dout, const int* __restrict__ ell,
                                                   const float* __restrict__ b, float* __restrict__ out,
                                                   int n, int do_relu, int so_mode) {
    int wv = threadIdx.x >> 6, lane = threadIdx.x & 63;
    int v = blockIdx.x * 4 + wv;
    if (v >= n) return;
    int dv = din[v];
    int cnt = min(dv, ELLW);
    int cl = ell[(size_t)v * ELLW + lane];   // full neighbor list, one wave load
    // ELL slots >= cnt are UNINITIALIZED (0xAA poison) -> clamp before any deref
    int cls = (lane < cnt) ? cl : 0;
    float scl = 1.f;
    if (so_mode) scl = rsqrtf((float)max(1, dout[cls]));   // per-neighbor out-scale
    float sx = 0.f, sy = 0.f;
    for (int j = 0; j < cnt; j += 8) {
        int cc[8]; float mk[8]; unsigned int t[8];
#pragma unroll
        for (int k = 0; k < 8; ++k) {
            int jj = j + k;
            int jc = jj < cnt ? jj : cnt - 1;
            cc[k] = __shfl(cls, jc);
            float sw = __shfl(scl, jc);
            mk[k] = (jj < cnt) ? sw : 0.f;
        }
#pragma unroll
        for (int k = 0; k < 8; ++k)
            t[k] = h[(size_t)cc[k] * 64 + lane];
#pragma unroll
        for (int k = 0; k < 8; ++k) {
            float x = __uint_as_float(t[k] << 16);
            float y = __uint_as_float(t[k] & 0xFFFF0000u);
            sx = fmaf(mk[k], x, sx);
            sy = fmaf(mk[k], y, sy);
        }
    }
    float sc = rsqrtf((float)max(1, dv));
    float2 bb = ((const float2*)b)[lane];
    float ox = sx * sc + bb.x;
    float oy = sy * sc + bb.y;
    if (do_relu) { ox = fmaxf(ox, 0.f); oy = fmaxf(oy, 0.f); }
    // NT store: agg is 51 MB streamed through L2 otherwise, evicting h2 re-reads
    nt_store_f2((float*)((float2*)out + (size_t)v * 64 + lane), ox, oy);
}

// ---------------- gather-aggregate (ELL), 40 cols f32 padded-48 rows (final layer) ----------------
__global__ __launch_bounds__(256) void k_gather40(const float* __restrict__ h, const int* __restrict__ din,
                                                  const int* __restrict__ ell,
                                                  const float* __restrict__ b, float* __restrict__ out, int n) {
    int wv = threadIdx.x >> 6, lane = threadIdx.x & 63;
    int v = blockIdx.x * 4 + wv;
    if (v >= n) return;
    int dv = din[v];
    int cnt = min(dv, ELLW);
    int cl = ell[(size_t)v * ELLW + lane];
    int cls = (lane < cnt) ? cl : 0;
    float s = 0.f;
    for (int j = 0; j < cnt; j += 8) {
        int cc[8]; float mk[8]; float t[8];
#pragma unroll
        for (int k = 0; k < 8; ++k) {
            int jj = j + k;
            cc[k] = __shfl(cls, jj < cnt ? jj : cnt - 1);
            mk[k] = (jj < cnt) ? 1.f : 0.f;
        }
        if (lane < 40) {
#pragma unroll
            for (int k = 0; k < 8; ++k) t[k] = h[(size_t)cc[k] * H40P + lane];
#pragma unroll
            for (int k = 0; k < 8; ++k) s = fmaf(mk[k], t[k], s);
        }
    }
    if (lane < 40) {
        out[(size_t)v * 40 + lane] = s * rsqrtf((float)max(1, dv)) + b[lane];
    }
}

extern "C" void kernel_launch(void* const* d_in, const int* in_sizes, int n_in,
                              void* d_out, int out_size, void* d_ws, size_t ws_size,
                              hipStream_t stream) {
    const float* feat = (const float*)d_in[0];
    const int*   src  = (const int*)d_in[1];
    const int*   dst  = (const int*)d_in[2];
    const float* W0   = (const float*)d_in[3];
    const float* b0   = (const float*)d_in[4];
    const float* W1   = (const float*)d_in[5];
    const float* b1   = (const float*)d_in[6];
    const float* W2   = (const float*)d_in[7];
    const float* b2   = (const float*)d_in[8];
    float* out = (float*)d_out;

    char* w = (char*)d_ws;
    int*   din       = (int*)w;    w += (size_t)NN * 4;
    int*   dout      = (int*)w;    w += (size_t)NN * 4;
    int*   ell       = (int*)w;    w += (size_t)NN * ELLW * 4;       // 25.6 MB
    unsigned int* h2 = (unsigned int*)w; w += (size_t)NN * 128 * 2;  // bf16 rows, 25.6 MB
    float* h40       = (float*)w;  w += (size_t)NN * H40P * 4;       // 19.2 MB (192 B rows)
    float* agg       = (float*)w;  w += (size_t)NN * 128 * 4;        // 51.2 MB

    // zero the two degree counters (contiguous at base)
    hipMemsetAsync(d_ws, 0, (size_t)NN * 8, stream);

    int gath_grid = (NN + 3) / 4;

    // fused: GEMM0 (unscaled feat@W0 -> h2) + ELL/degree build (independent halves)
    k_build_gemm0<<<GEMMN + BUILDN, 256, 0, stream>>>(src, dst, din, dout, ell, feat, W0, h2);
    // layer 0 gather: applies per-neighbor so = rsqrt(dout[u]) and si inline
    k_gather128<<<gath_grid, 256, 0, stream>>>(h2, din, dout, ell, b0, agg, NN, 1, 1);
    // layer 1: gemm scales rows by rsqrt(dout) inline
    k_gemm128<<<GEMMN, 256, 0, stream>>>(agg, dout, W1, h2, NN);
    k_gather128<<<gath_grid, 256, 0, stream>>>(h2, din, dout, ell, b1, agg, NN, 1, 0);
    // layer 2 (40 cols f32 padded rows, no relu), writes d_out via gather40
    k_gemm40<<<(NN + 63) / 64, 320, 0, stream>>>(agg, dout, W2, h40, NN);
    k_gather40<<<gath_grid, 256, 0, stream>>>(h40, din, ell, b2, out, NN);
}

// Round 10
// 567.039 us; speedup vs baseline: 1.0364x; 1.0035x over previous
//
#include <hip/hip_runtime.h>

#define NN 100000
#define EE 1600000
#define ELLW 64   // max in-degree; Poisson(16) over 100K nodes -> max ~40, 64 safe
#define NXCD 8
#define RNG ((NN + NXCD - 1) / NXCD)   // 12500 nodes per XCD partition
#define GEMMN ((NN + 31) / 32)         // 3125 gemm blocks (32-row tiles, 16 KB LDS)
#define BUILDN ((EE / 256) * NXCD)     // 50000 build blocks; 53125 = 3125*17 total

// bf16 round-to-nearest-even pack of two floats -> (lo=a, hi=b)
__device__ __forceinline__ unsigned int pack_bf2(float a, float b) {
    unsigned int ua = __float_as_uint(a);
    ua += 0x7FFFu + ((ua >> 16) & 1u);
    unsigned int ub = __float_as_uint(b);
    ub += 0x7FFFu + ((ub >> 16) & 1u);
    return (ua >> 16) | (ub & 0xFFFF0000u);
}

__device__ __forceinline__ void nt_store_f2(float* p, float x, float y) {
    unsigned long long v = (unsigned long long)__float_as_uint(x) |
                           ((unsigned long long)__float_as_uint(y) << 32);
    __builtin_nontemporal_store(v, (unsigned long long*)p);
}

// ---------------- GEMM body: Ybf16[32 rows x 128] = (X*scale?) @ W, 256 threads, 16 KB LDS ----
__device__ __forceinline__ void gemm128_body(const float* __restrict__ X, const int* __restrict__ dout,
                                             const float* __restrict__ W, unsigned int* __restrict__ Y,
                                             int n, int row0, int tid, float* Xs, int scaled) {
    const float4* X4 = (const float4*)X;
#pragma unroll
    for (int idx = tid; idx < 1024; idx += 256) {
        int r = idx & 31, c4 = idx >> 5;
        int row = row0 + r;
        float4 v = make_float4(0.f, 0.f, 0.f, 0.f);
        float s = 0.f;
        if (row < n) {
            v = X4[(size_t)row * 32 + c4];
            s = scaled ? rsqrtf((float)max(1, dout[row])) : 1.f;
        }
        Xs[(c4 * 4 + 0) * 32 + r] = v.x * s;
        Xs[(c4 * 4 + 1) * 32 + r] = v.y * s;
        Xs[(c4 * 4 + 2) * 32 + r] = v.z * s;
        Xs[(c4 * 4 + 3) * 32 + r] = v.w * s;
    }
    __syncthreads();
    int cg = tid & 31;   // cols 4cg..4cg+3
    int rg = tid >> 5;   // rows 4rg..4rg+3
    float a[4][4];
#pragma unroll
    for (int r = 0; r < 4; ++r)
#pragma unroll
        for (int c = 0; c < 4; ++c) a[r][c] = 0.f;
    const float4* W4 = (const float4*)W;
#pragma unroll 4
    for (int k = 0; k < 128; ++k) {
        float4 xv = *(const float4*)&Xs[k * 32 + rg * 4];
        float4 wv = W4[k * 32 + cg];
        float xr[4] = {xv.x, xv.y, xv.z, xv.w};
        float wc[4] = {wv.x, wv.y, wv.z, wv.w};
#pragma unroll
        for (int r = 0; r < 4; ++r)
#pragma unroll
            for (int c = 0; c < 4; ++c) a[r][c] = fmaf(xr[r], wc[c], a[r][c]);
    }
    int rbase = row0 + rg * 4;
    uint2* Y2 = (uint2*)Y;   // 32 uint2 per 128-col bf16 row
#pragma unroll
    for (int r = 0; r < 4; ++r) {
        if (rbase + r < n) {
            Y2[(size_t)(rbase + r) * 32 + cg] =
                make_uint2(pack_bf2(a[r][0], a[r][1]), pack_bf2(a[r][2], a[r][3]));
        }
    }
}

// ---------------- fused: interleaved GEMM0 + XCD-partitioned ELL build ----------------
// Blocks drain in dispatch order (r9: GEMM-first gave ZERO overlap). Every 17th
// block is a GEMM block so the resident mix stays ~6% GEMM / 94% build for the
// whole kernel -> GEMM VALU work hides under the atomic-latency-bound build.
__global__ __launch_bounds__(256) void k_build_gemm0(const int* __restrict__ src, const int* __restrict__ dst,
                                                     int* __restrict__ din, int* __restrict__ dout,
                                                     int* __restrict__ ell,
                                                     const float* __restrict__ X, const float* __restrict__ W,
                                                     unsigned int* __restrict__ Y) {
    __shared__ float Xs[128 * 32];
    int tid = threadIdx.x;
    int q = blockIdx.x / 17, rem = blockIdx.x % 17;
    if (rem == 16) {   // GEMM block q (q in [0, GEMMN))
        gemm128_body(X, nullptr, W, Y, NN, q * 32, tid, Xs, 0);
        return;
    }
    int idx = q * 16 + rem;   // build index in [0, BUILDN)
    int r = idx & (NXCD - 1);
    int slice = idx >> 3;
    int i = slice * 256 + tid;
    if (i >= EE) return;
    int s = __builtin_nontemporal_load(&src[i]);
    int d = __builtin_nontemporal_load(&dst[i]);
    int lo = r * RNG, hi = lo + RNG;
    if (d >= lo && d < hi) {
        int p = atomicAdd(&din[d], 1);
        if (p < ELLW) ell[(size_t)d * ELLW + p] = s;
    }
    if (s >= lo && s < hi) {
        atomicAdd(&dout[s], 1);
    }
}

// ---------------- standalone GEMM (layer 1): scaled by rsqrt(dout) inline ----------------
__global__ __launch_bounds__(256) void k_gemm128(const float* __restrict__ X, const int* __restrict__ dout,
                                                 const float* __restrict__ W, unsigned int* __restrict__ Y, int n) {
    __shared__ float Xs[128 * 32];
    gemm128_body(X, dout, W, Y, n, blockIdx.x * 32, threadIdx.x, Xs, 1);
}

// ---------------- GEMM: Ybf16[n x 64pad] = (X * rsqrt(dout)) @ W[128 x 40], 320 threads ------
// Output rows: 40 bf16 cols packed in 20 uints, padded to 32 uints = 128 B = 2 lines.
__global__ __launch_bounds__(320) void k_gemm40(const float* __restrict__ X, const int* __restrict__ dout,
                                                const float* __restrict__ W, unsigned int* __restrict__ Y, int n) {
    __shared__ float Xs[128 * 64];
    int tid = threadIdx.x;
    int row0 = blockIdx.x * 64;
    const float4* X4 = (const float4*)X;
    for (int idx = tid; idx < 2048; idx += 320) {
        int r = idx & 63, c4 = idx >> 6;
        int row = row0 + r;
        float4 v = make_float4(0.f, 0.f, 0.f, 0.f);
        float s = 0.f;
        if (row < n) { v = X4[(size_t)row * 32 + c4]; s = rsqrtf((float)max(1, dout[row])); }
        Xs[(c4 * 4 + 0) * 64 + r] = v.x * s;
        Xs[(c4 * 4 + 1) * 64 + r] = v.y * s;
        Xs[(c4 * 4 + 2) * 64 + r] = v.z * s;
        Xs[(c4 * 4 + 3) * 64 + r] = v.w * s;
    }
    __syncthreads();
    int cg = tid % 20;   // cols 2cg, 2cg+1
    int rg = tid / 20;   // rows 4rg..4rg+3
    float a0x=0,a0y=0, a1x=0,a1y=0, a2x=0,a2y=0, a3x=0,a3y=0;
    const float2* W2 = (const float2*)W;
#pragma unroll 4
    for (int k = 0; k < 128; ++k) {
        float4 xv = *(const float4*)&Xs[k * 64 + rg * 4];
        float2 wv = W2[k * 20 + cg];
        a0x += xv.x * wv.x; a0y += xv.x * wv.y;
        a1x += xv.y * wv.x; a1y += xv.y * wv.y;
        a2x += xv.z * wv.x; a2y += xv.z * wv.y;
        a3x += xv.w * wv.x; a3y += xv.w * wv.y;
    }
    int rbase = row0 + rg * 4;
    if (rbase + 0 < n) Y[(size_t)(rbase + 0) * 32 + cg] = pack_bf2(a0x, a0y);
    if (rbase + 1 < n) Y[(size_t)(rbase + 1) * 32 + cg] = pack_bf2(a1x, a1y);
    if (rbase + 2 < n) Y[(size_t)(rbase + 2) * 32 + cg] = pack_bf2(a2x, a2y);
    if (rbase + 3 < n) Y[(size_t)(rbase + 3) * 32 + cg] = pack_bf2(a3x, a3y);
}

// ---------------- gather-aggregate (ELL), 128 cols bf16, si inline; optional per-neighbor so ----
__global__ __launch_bounds__(256) void k_gather128(const unsigned int* __restrict__ h, const int* __restrict__ din,
                                                   const int* __restrict__ dout, const int* __restrict__ ell,
                                                   const float* __restrict__ b, float* __restrict__ out,
                                                   int n, int do_relu, int so_mode) {
    int wv = threadIdx.x >> 6, lane = threadIdx.x & 63;
    int v = blockIdx.x * 4 + wv;
    if (v >= n) return;
    int dv = din[v];
    int cnt = min(dv, ELLW);
    int cl = ell[(size_t)v * ELLW + lane];   // full neighbor list, one wave load
    // ELL slots >= cnt are UNINITIALIZED (0xAA poison) -> clamp before any deref
    int cls = (lane < cnt) ? cl : 0;
    float scl = 1.f;
    if (so_mode) scl = rsqrtf((float)max(1, dout[cls]));   // per-neighbor out-scale
    float sx = 0.f, sy = 0.f;
    for (int j = 0; j < cnt; j += 8) {
        int cc[8]; float mk[8]; unsigned int t[8];
#pragma unroll
        for (int k = 0; k < 8; ++k) {
            int jj = j + k;
            int jc = jj < cnt ? jj : cnt - 1;
            cc[k] = __shfl(cls, jc);
            float sw = __shfl(scl, jc);
            mk[k] = (jj < cnt) ? sw : 0.f;
        }
#pragma unroll
        for (int k = 0; k < 8; ++k)
            t[k] = h[(size_t)cc[k] * 64 + lane];
#pragma unroll
        for (int k = 0; k < 8; ++k) {
            float x = __uint_as_float(t[k] << 16);
            float y = __uint_as_float(t[k] & 0xFFFF0000u);
            sx = fmaf(mk[k], x, sx);
            sy = fmaf(mk[k], y, sy);
        }
    }
    float sc = rsqrtf((float)max(1, dv));
    float2 bb = ((const float2*)b)[lane];
    float ox = sx * sc + bb.x;
    float oy = sy * sc + bb.y;
    if (do_relu) { ox = fmaxf(ox, 0.f); oy = fmaxf(oy, 0.f); }
    // NT store: agg is 51 MB streamed; skip L2 so h2 re-reads survive
    nt_store_f2((float*)((float2*)out + (size_t)v * 64 + lane), ox, oy);
}

// ---------------- gather-aggregate (ELL), 40 cols bf16 padded-128B rows (final layer) ----------------
__global__ __launch_bounds__(256) void k_gather40(const unsigned short* __restrict__ h, const int* __restrict__ din,
                                                  const int* __restrict__ ell,
                                                  const float* __restrict__ b, float* __restrict__ out, int n) {
    int wv = threadIdx.x >> 6, lane = threadIdx.x & 63;
    int v = blockIdx.x * 4 + wv;
    if (v >= n) return;
    int dv = din[v];
    int cnt = min(dv, ELLW);
    int cl = ell[(size_t)v * ELLW + lane];
    int cls = (lane < cnt) ? cl : 0;
    float s = 0.f;
    for (int j = 0; j < cnt; j += 8) {
        int cc[8]; float mk[8]; unsigned short t[8];
#pragma unroll
        for (int k = 0; k < 8; ++k) {
            int jj = j + k;
            cc[k] = __shfl(cls, jj < cnt ? jj : cnt - 1);
            mk[k] = (jj < cnt) ? 1.f : 0.f;
        }
        if (lane < 40) {
#pragma unroll
            for (int k = 0; k < 8; ++k) t[k] = h[(size_t)cc[k] * 64 + lane];  // 64-short rows = 128 B
#pragma unroll
            for (int k = 0; k < 8; ++k)
                s = fmaf(mk[k], __uint_as_float((unsigned int)t[k] << 16), s);
        }
    }
    if (lane < 40) {
        out[(size_t)v * 40 + lane] = s * rsqrtf((float)max(1, dv)) + b[lane];
    }
}

extern "C" void kernel_launch(void* const* d_in, const int* in_sizes, int n_in,
                              void* d_out, int out_size, void* d_ws, size_t ws_size,
                              hipStream_t stream) {
    const float* feat = (const float*)d_in[0];
    const int*   src  = (const int*)d_in[1];
    const int*   dst  = (const int*)d_in[2];
    const float* W0   = (const float*)d_in[3];
    const float* b0   = (const float*)d_in[4];
    const float* W1   = (const float*)d_in[5];
    const float* b1   = (const float*)d_in[6];
    const float* W2   = (const float*)d_in[7];
    const float* b2   = (const float*)d_in[8];
    float* out = (float*)d_out;

    char* w = (char*)d_ws;
    int*   din       = (int*)w;    w += (size_t)NN * 4;
    int*   dout      = (int*)w;    w += (size_t)NN * 4;
    int*   ell       = (int*)w;    w += (size_t)NN * ELLW * 4;       // 25.6 MB
    unsigned int* h2 = (unsigned int*)w; w += (size_t)NN * 128 * 2;  // bf16 rows, 25.6 MB
    unsigned int* h40 = (unsigned int*)w; w += (size_t)NN * 32 * 4;  // bf16 40-col rows padded to 128 B
    float* agg       = (float*)w;  w += (size_t)NN * 128 * 4;        // 51.2 MB

    // zero the two degree counters (contiguous at base)
    hipMemsetAsync(d_ws, 0, (size_t)NN * 8, stream);

    int gath_grid = (NN + 3) / 4;

    // fused: interleaved GEMM0 (unscaled feat@W0 -> h2) + ELL/degree build
    k_build_gemm0<<<GEMMN * 17, 256, 0, stream>>>(src, dst, din, dout, ell, feat, W0, h2);
    // layer 0 gather: applies per-neighbor so = rsqrt(dout[u]) and si inline
    k_gather128<<<gath_grid, 256, 0, stream>>>(h2, din, dout, ell, b0, agg, NN, 1, 1);
    // layer 1: gemm scales rows by rsqrt(dout) inline
    k_gemm128<<<GEMMN, 256, 0, stream>>>(agg, dout, W1, h2, NN);
    k_gather128<<<gath_grid, 256, 0, stream>>>(h2, din, dout, ell, b1, agg, NN, 1, 0);
    // layer 2: gemm -> bf16 padded rows; gather40 writes d_out
    k_gemm40<<<(NN + 63) / 64, 320, 0, stream>>>(agg, dout, W2, h40, NN);
    k_gather40<<<gath_grid, 256, 0, stream>>>((const unsigned short*)h40, din, ell, b2, out, NN);
}